// Round 3
// baseline (259.013 us; speedup 1.0000x reference)
//
#include <hip/hip_runtime.h>
#include <hip/hip_bf16.h>
#include <stdint.h>

#define N_B   4
#define C_CH  256
#define MID   32
#define S_LEN 4096

typedef __attribute__((ext_vector_type(8))) short short8;
typedef __attribute__((ext_vector_type(4))) float f32x4;
typedef __attribute__((ext_vector_type(2))) unsigned int u32x2;
typedef __attribute__((ext_vector_type(4))) unsigned int u32x4;

// workspace layout (bytes)
#define OFF_XBF   ((size_t)0)                        // [4][4096][256] bf16 = 8 MB
#define OFF_V     (OFF_XBF + (size_t)(8*1024*1024))  // [4][256][4096] bf16 = 8 MB
#define OFF_QT_HI (OFF_V + (size_t)(8*1024*1024))    // [4][4096][32] bf16 = 1 MB
#define OFF_QT_LO (OFF_QT_HI + (size_t)(1024*1024))
#define OFF_KT_HI (OFF_QT_LO + (size_t)(1024*1024))  // [4][4096][32] bf16 = 1 MB
#define OFF_KT_LO (OFF_KT_HI + (size_t)(1024*1024))
#define OFF_WVBF  (OFF_KT_LO + (size_t)(1024*1024))  // [256][256] bf16 = 128 KB
#define OFF_WQT   (OFF_WVBF + (size_t)(128*1024))    // [256][32] f32 = 32 KB
#define OFF_WKT   (OFF_WQT + (size_t)(32*1024))      // [256][32] f32 = 32 KB

__device__ __forceinline__ unsigned short f2bf(float f) {
    __hip_bfloat16 h = __float2bfloat16(f);
    return *(unsigned short*)&h;
}
__device__ __forceinline__ float bf2f(unsigned short u) {
    return __bfloat162float(*(__hip_bfloat16*)&u);
}
__device__ __forceinline__ unsigned pk2(float a, float b) {
    return (unsigned)f2bf(a) | ((unsigned)f2bf(b) << 16);
}

// ---------- prep: x [n][c][t] f32 -> xbf [n][t][c] bf16 ----------
__global__ __launch_bounds__(256) void prep_xbf(const float* __restrict__ x,
                                                unsigned short* __restrict__ xbf)
{
    const int tt = blockIdx.x;
    const int cc = blockIdx.y;
    const int n  = blockIdx.z;
    const int l  = threadIdx.x & 63;
    const int cw = threadIdx.x >> 6;
    const int t  = tt * 64 + l;
    const int c0 = cc * 64 + cw * 16;

    unsigned short v[16];
#pragma unroll
    for (int k = 0; k < 16; k++)
        v[k] = f2bf(x[((size_t)n * C_CH + c0 + k) * S_LEN + t]);

    unsigned p[8];
#pragma unroll
    for (int j = 0; j < 8; j++) p[j] = (unsigned)v[2*j] | ((unsigned)v[2*j+1] << 16);
    unsigned short* o = xbf + ((size_t)n * S_LEN + t) * C_CH + c0;
    u32x4 a = { p[0], p[1], p[2], p[3] };
    u32x4 b = { p[4], p[5], p[6], p[7] };
    *(u32x4*)(o)     = a;
    *(u32x4*)(o + 8) = b;
}

// ---------- wprep ----------
__global__ __launch_bounds__(256) void wprep(const float* __restrict__ Wq,
                                             const float* __restrict__ Wk,
                                             const float* __restrict__ Wv,
                                             unsigned short* __restrict__ wvbf,
                                             float* __restrict__ wqT,
                                             float* __restrict__ wkT)
{
    const int b = blockIdx.x;
    if (b < 64) {
        int i = b * 1024 + threadIdx.x * 4;
        f32x4 w = *(const f32x4*)(Wv + i);
        u32x2 pk;
        pk[0] = pk2(w[0], w[1]);
        pk[1] = pk2(w[2], w[3]);
        *(u32x2*)(wvbf + i) = pk;
    } else if (b == 64) {
        int c = threadIdx.x;
#pragma unroll
        for (int m = 0; m < 32; m++) wqT[c * 32 + m] = Wq[m * C_CH + c];
    } else {
        int c = threadIdx.x;
#pragma unroll
        for (int m = 0; m < 32; m++) wkT[c * 32 + m] = Wk[m * C_CH + c];
    }
}

// ---------- fused Q/K projection (fp32 VALU), plain [n][s][32] hi/lo ----------
__global__ __launch_bounds__(512) void qk_proj(
    const float* __restrict__ x, const float* __restrict__ wqT, const float* __restrict__ wkT,
    const float* __restrict__ bq, const float* __restrict__ bk,
    unsigned short* __restrict__ qt_hi, unsigned short* __restrict__ qt_lo,
    unsigned short* __restrict__ kt_hi, unsigned short* __restrict__ kt_lo)
{
    const int n  = blockIdx.y;
    const int S0 = blockIdx.x * 64;
    const int w  = threadIdx.x >> 6;
    const int l  = threadIdx.x & 63;
    const int s  = S0 + l;
    const bool isK = (w >= 4);
    const int m0 = (w & 3) * 8;
    const float* WT   = isK ? wkT : wqT;
    const float* bias = isK ? bk : bq;

    float acc[8];
#pragma unroll
    for (int k = 0; k < 8; k++) acc[k] = bias[m0 + k];

    const float* xp = x + (size_t)n * C_CH * S_LEN + s;
#pragma unroll 4
    for (int c = 0; c < C_CH; c++) {
        float xv = xp[(size_t)c * S_LEN];
        f32x4 w0 = *(const f32x4*)(WT + c * 32 + m0);
        f32x4 w1 = *(const f32x4*)(WT + c * 32 + m0 + 4);
        acc[0] = fmaf(w0[0], xv, acc[0]);
        acc[1] = fmaf(w0[1], xv, acc[1]);
        acc[2] = fmaf(w0[2], xv, acc[2]);
        acc[3] = fmaf(w0[3], xv, acc[3]);
        acc[4] = fmaf(w1[0], xv, acc[4]);
        acc[5] = fmaf(w1[1], xv, acc[5]);
        acc[6] = fmaf(w1[2], xv, acc[6]);
        acc[7] = fmaf(w1[3], xv, acc[7]);
    }

    unsigned hv[4], lv[4];
#pragma unroll
    for (int k2 = 0; k2 < 4; k2++) {
        float f0 = acc[2*k2], f1 = acc[2*k2+1];
        unsigned short h0 = f2bf(f0), h1 = f2bf(f1);
        unsigned short l0 = f2bf(f0 - bf2f(h0)), l1 = f2bf(f1 - bf2f(h1));
        hv[k2] = (unsigned)h0 | ((unsigned)h1 << 16);
        lv[k2] = (unsigned)l0 | ((unsigned)l1 << 16);
    }
    u32x4 vh = { hv[0], hv[1], hv[2], hv[3] };
    u32x4 vl = { lv[0], lv[1], lv[2], lv[3] };

    size_t o = ((size_t)n * S_LEN + s) * MID + m0;
    if (!isK) {
        *(u32x4*)(qt_hi + o) = vh;
        *(u32x4*)(qt_lo + o) = vl;
    } else {
        *(u32x4*)(kt_hi + o) = vh;
        *(u32x4*)(kt_lo + o) = vl;
    }
}

// ---------- V projection: bf16 MFMA GEMM, V[n][d][t] ----------
__global__ __launch_bounds__(256) void v_gemm(
    const unsigned short* __restrict__ xbf, const unsigned short* __restrict__ wvbf,
    const float* __restrict__ bv, unsigned short* __restrict__ V)
{
    const int n  = blockIdx.y;
    const int t0 = blockIdx.x * 64;
    const int w  = threadIdx.x >> 6;
    const int l  = threadIdx.x & 63;
    const int l16 = l & 15, lq = l >> 4;

    f32x4 acc[16];
#pragma unroll
    for (int i = 0; i < 16; i++) acc[i] = (f32x4){0.f, 0.f, 0.f, 0.f};

    const unsigned short* xrow = xbf + ((size_t)n * S_LEN + t0 + w * 16 + l16) * C_CH;
#pragma unroll
    for (int kk = 0; kk < 8; kk++) {
        short8 a = *(const short8*)(xrow + kk * 32 + lq * 8);
#pragma unroll
        for (int df = 0; df < 16; df++) {
            short8 b = *(const short8*)(wvbf + (size_t)(df * 16 + l16) * C_CH + kk * 32 + lq * 8);
            acc[df] = __builtin_amdgcn_mfma_f32_16x16x32_bf16(a, b, acc[df], 0, 0, 0);
        }
    }

    const int tb = t0 + w * 16 + lq * 4;
#pragma unroll
    for (int df = 0; df < 16; df++) {
        int d = df * 16 + l16;
        float bvv = bv[d];
        u32x2 pk;
        pk[0] = pk2(acc[df][0] + bvv, acc[df][1] + bvv);
        pk[1] = pk2(acc[df][2] + bvv, acc[df][3] + bvv);
        *(u32x2*)(V + ((size_t)n * C_CH + d) * S_LEN + tb) = pk;
    }
}

// ---------- fused flash attention, in-block split-K over t, + residual ----------
__global__ __launch_bounds__(512, 4) void attn(
    const unsigned short* __restrict__ qt_hi, const unsigned short* __restrict__ qt_lo,
    const unsigned short* __restrict__ kt_hi, const unsigned short* __restrict__ kt_lo,
    const unsigned short* __restrict__ V, const float* __restrict__ x,
    const float* __restrict__ gamma, float* __restrict__ out)
{
    const int bid = blockIdx.x;
    const int n   = bid & 3;               // one n per XCD (bid%8 -> XCD, xcd&3 = n)
    const int S0  = (bid >> 2) * 32;
    const int tid = threadIdx.x;
    const int w   = tid >> 6, l = tid & 63;
    const int h   = w >> 2;                 // t-half
    const int role = w & 3;                 // 0,1: QK+softmax+PV ; 2,3: PV only
    const int l16 = l & 15, lq = l >> 4;

    __shared__ __align__(16) unsigned char plds[2][32 * 128];  // P per half, swizzled
    __shared__ __align__(16) float alds[2][32];
    __shared__ __align__(16) float mlds_m[2][32];
    __shared__ __align__(16) float mlds_l[2][32];
    __shared__ __align__(16) unsigned char mrg[16384];         // merge buffer

    const bool isQK = (role < 2);

    short8 qhi = {0,0,0,0,0,0,0,0}, qlo = {0,0,0,0,0,0,0,0};
    if (isQK) {
        size_t qoff = ((size_t)n * S_LEN + S0 + role * 16 + l16) * MID + lq * 8;
        qhi = *(const short8*)(qt_hi + qoff);
        qlo = *(const short8*)(qt_lo + qoff);
    }

    f32x4 acc[2][4];
#pragma unroll
    for (int a = 0; a < 2; a++)
#pragma unroll
        for (int b = 0; b < 4; b++) acc[a][b] = (f32x4){0.f, 0.f, 0.f, 0.f};
    float m_run = -__builtin_inff(), l_run = 0.f;

    const unsigned short* Vb = V + (size_t)n * C_CH * S_LEN;
    const unsigned short* Kh = kt_hi + (size_t)n * S_LEN * MID;
    const unsigned short* Kl = kt_lo + (size_t)n * S_LEN * MID;
    const int tbase = h * 2048;

    for (int ti = 0; ti < 32; ti++) {
        const int t0 = tbase + ti * 64;
        __syncthreads();                       // B1: plds[h] free (prev PV reads done)

        // V fragments for this tile (direct global, L2-hot; consumed after B2)
        short8 vfr[4][2];
#pragma unroll
        for (int df = 0; df < 4; df++)
#pragma unroll
            for (int kk = 0; kk < 2; kk++)
                vfr[df][kk] = *(const short8*)(Vb + (size_t)(role * 64 + df * 16 + l16) * S_LEN
                                               + t0 + kk * 32 + lq * 8);

        if (isQK) {
            // swapped QK^T: D[t][s], col s = l16 (lane-local row!), row t = lq*4+r
            f32x4 sD[4];
#pragma unroll
            for (int tf = 0; tf < 4; tf++) {
                size_t ko = (size_t)(t0 + tf * 16 + l16) * MID + lq * 8;
                short8 khi = *(const short8*)(Kh + ko);
                short8 klo = *(const short8*)(Kl + ko);
                f32x4 c0 = (f32x4){0.f, 0.f, 0.f, 0.f};
                c0 = __builtin_amdgcn_mfma_f32_16x16x32_bf16(khi, qhi, c0, 0, 0, 0);
                c0 = __builtin_amdgcn_mfma_f32_16x16x32_bf16(khi, qlo, c0, 0, 0, 0);
                c0 = __builtin_amdgcn_mfma_f32_16x16x32_bf16(klo, qhi, c0, 0, 0, 0);
                sD[tf] = c0;
            }
            // online softmax: lane owns s-row = role*16+l16; 16 in-lane t + 2 shuffles
            float t0m = fmaxf(fmaxf(sD[0][0], sD[0][1]), fmaxf(sD[0][2], sD[0][3]));
            float t1m = fmaxf(fmaxf(sD[1][0], sD[1][1]), fmaxf(sD[1][2], sD[1][3]));
            float t2m = fmaxf(fmaxf(sD[2][0], sD[2][1]), fmaxf(sD[2][2], sD[2][3]));
            float t3m = fmaxf(fmaxf(sD[3][0], sD[3][1]), fmaxf(sD[3][2], sD[3][3]));
            float tmax = fmaxf(fmaxf(t0m, t1m), fmaxf(t2m, t3m));
            tmax = fmaxf(tmax, __shfl_xor(tmax, 16));
            tmax = fmaxf(tmax, __shfl_xor(tmax, 32));
            float mn = fmaxf(m_run, tmax);
            float al = __expf(m_run - mn);
            float p[4][4];
            float ps = 0.f;
#pragma unroll
            for (int tf = 0; tf < 4; tf++)
#pragma unroll
                for (int r = 0; r < 4; r++) {
                    p[tf][r] = __expf(sD[tf][r] - mn);
                    ps += p[tf][r];
                }
            ps += __shfl_xor(ps, 16);
            ps += __shfl_xor(ps, 32);
            l_run = al * l_run + ps;
            m_run = mn;

            // P -> LDS: packed b64 writes (pairs along t), XOR-swizzled
            const int row = role * 16 + l16;
            const int swz = (row & 7) << 4;
            unsigned char* pb = &plds[h][0] + row * 128;
#pragma unroll
            for (int tf = 0; tf < 4; tf++) {
                u32x2 wpk;
                wpk[0] = pk2(p[tf][0], p[tf][1]);
                wpk[1] = pk2(p[tf][2], p[tf][3]);
                *(u32x2*)(pb + (((tf * 32 + lq * 8)) ^ swz)) = wpk;
            }
            if (lq == 0) alds[h][row] = al;
        }
        __syncthreads();                       // B2: P ready

        // rescale accumulators
#pragma unroll
        for (int sf = 0; sf < 2; sf++) {
            f32x4 av = *(const f32x4*)(&alds[h][sf * 16 + lq * 4]);
#pragma unroll
            for (int df = 0; df < 4; df++) {
                acc[sf][df][0] *= av[0]; acc[sf][df][1] *= av[1];
                acc[sf][df][2] *= av[2]; acc[sf][df][3] *= av[3];
            }
        }
        // PV
#pragma unroll
        for (int kk = 0; kk < 2; kk++) {
            short8 pa[2];
#pragma unroll
            for (int sf = 0; sf < 2; sf++) {
                int row = sf * 16 + l16;
                pa[sf] = *(const short8*)(&plds[h][0] + row * 128
                                          + ((kk * 64 + lq * 16) ^ ((row & 7) << 4)));
            }
#pragma unroll
            for (int df = 0; df < 4; df++)
#pragma unroll
                for (int sf = 0; sf < 2; sf++)
                    acc[sf][df] = __builtin_amdgcn_mfma_f32_16x16x32_bf16(pa[sf], vfr[df][kk],
                                                                          acc[sf][df], 0, 0, 0);
        }
    }

    // merge halves: (m,l) then acc chunks through LDS
    if (isQK && lq == 0) {
        mlds_m[h][role * 16 + l16] = m_run;
        mlds_l[h][role * 16 + l16] = l_run;
    }
    __syncthreads();

    const float g = gamma[0];
#pragma unroll
    for (int ck = 0; ck < 2; ck++) {         // chunk = sf
        if (h == 1) {
#pragma unroll
            for (int df = 0; df < 4; df++)
                *(f32x4*)(&mrg[(((role * 4 + df) * 64) + l) * 16]) = acc[ck][df];
        }
        __syncthreads();
        if (h == 0) {
            float e0[4], e1[4], rden[4];
#pragma unroll
            for (int r = 0; r < 4; r++) {
                int s = ck * 16 + lq * 4 + r;
                float m0 = mlds_m[0][s], l0 = mlds_l[0][s];
                float m1 = mlds_m[1][s], l1 = mlds_l[1][s];
                float M  = fmaxf(m0, m1);
                e0[r] = __expf(m0 - M);
                e1[r] = __expf(m1 - M);
                rden[r] = 1.f / (e0[r] * l0 + e1[r] * l1);
            }
#pragma unroll
            for (int df = 0; df < 4; df++) {
                f32x4 o1 = *(const f32x4*)(&mrg[(((role * 4 + df) * 64) + l) * 16]);
                int d = role * 64 + df * 16 + l16;
                size_t base = ((size_t)n * C_CH + d) * S_LEN + S0 + ck * 16 + lq * 4;
                f32x4 xr = *(const f32x4*)(x + base);
                f32x4 ov;
#pragma unroll
                for (int r = 0; r < 4; r++)
                    ov[r] = xr[r] + g * (acc[ck][df][r] * e0[r] + o1[r] * e1[r]) * rden[r];
                *(f32x4*)(out + base) = ov;
            }
        }
        __syncthreads();
    }
}

extern "C" void kernel_launch(void* const* d_in, const int* in_sizes, int n_in,
                              void* d_out, int out_size, void* d_ws, size_t ws_size,
                              hipStream_t stream) {
    const float* x     = (const float*)d_in[0];
    const float* Wq    = (const float*)d_in[1];
    const float* bq    = (const float*)d_in[2];
    const float* Wk    = (const float*)d_in[3];
    const float* bk    = (const float*)d_in[4];
    const float* Wv    = (const float*)d_in[5];
    const float* bv    = (const float*)d_in[6];
    const float* gamma = (const float*)d_in[7];
    float* out = (float*)d_out;

    unsigned char* ws = (unsigned char*)d_ws;
    unsigned short* xbf   = (unsigned short*)(ws + OFF_XBF);
    unsigned short* V     = (unsigned short*)(ws + OFF_V);
    unsigned short* qt_hi = (unsigned short*)(ws + OFF_QT_HI);
    unsigned short* qt_lo = (unsigned short*)(ws + OFF_QT_LO);
    unsigned short* kt_hi = (unsigned short*)(ws + OFF_KT_HI);
    unsigned short* kt_lo = (unsigned short*)(ws + OFF_KT_LO);
    unsigned short* wvbf  = (unsigned short*)(ws + OFF_WVBF);
    float*          wqT   = (float*)(ws + OFF_WQT);
    float*          wkT   = (float*)(ws + OFF_WKT);

    prep_xbf<<<dim3(64, 4, 4), dim3(256), 0, stream>>>(x, xbf);
    wprep<<<dim3(66), dim3(256), 0, stream>>>(Wq, Wk, Wv, wvbf, wqT, wkT);
    qk_proj<<<dim3(64, 4), dim3(512), 0, stream>>>(x, wqT, wkT, bq, bk,
                                                   qt_hi, qt_lo, kt_hi, kt_lo);
    v_gemm<<<dim3(64, 4), dim3(256), 0, stream>>>(xbf, wvbf, bv, V);
    attn<<<dim3(512), dim3(512), 0, stream>>>(qt_hi, qt_lo, kt_hi, kt_lo, V,
                                              x, gamma, out);
}

// Round 4
// 154.732 us; speedup vs baseline: 1.6739x; 1.6739x over previous
//
#include <hip/hip_runtime.h>
#include <hip/hip_bf16.h>
#include <stdint.h>

#define S_LEN 4096
#define LOG2E 1.44269504088896f

typedef __attribute__((ext_vector_type(8)))  short short8;
typedef __attribute__((ext_vector_type(4)))  float f32x4;
typedef __attribute__((ext_vector_type(16))) float f32x16;
typedef __attribute__((ext_vector_type(2)))  unsigned int u32x2;
typedef __attribute__((ext_vector_type(4)))  unsigned int u32x4;

// workspace (bytes)
#define OFF_XHI   ((size_t)0)                         // [4][4096][256] bf16 = 8MB
#define OFF_XLO_V (OFF_XHI + (size_t)(8u<<20))        // x_lo, later overwritten by V (8MB)
#define OFF_QT_HI (OFF_XLO_V + (size_t)(8u<<20))      // [4][4096][32] = 1MB each
#define OFF_QT_LO (OFF_QT_HI + (size_t)(1u<<20))
#define OFF_KT_HI (OFF_QT_LO + (size_t)(1u<<20))
#define OFF_KT_LO (OFF_KT_HI + (size_t)(1u<<20))
#define OFF_WVBF  (OFF_KT_LO + (size_t)(1u<<20))      // 128KB
#define OFF_WQH   (OFF_WVBF + (size_t)(128*1024))     // 16KB each
#define OFF_WQL   (OFF_WQH + (size_t)(16*1024))
#define OFF_WKH   (OFF_WQL + (size_t)(16*1024))
#define OFF_WKL   (OFF_WKH + (size_t)(16*1024))

__device__ __forceinline__ unsigned short f2bf(float f) {
    __hip_bfloat16 h = __float2bfloat16(f);
    return *(unsigned short*)&h;
}
__device__ __forceinline__ float bf2f(unsigned short u) {
    return __bfloat162float(*(__hip_bfloat16*)&u);
}
__device__ __forceinline__ unsigned pk2(float a, float b) {
    return (unsigned)f2bf(a) | ((unsigned)f2bf(b) << 16);
}
union S8U { u32x4 u; short8 s; };

#define Z16 {0.f,0.f,0.f,0.f,0.f,0.f,0.f,0.f,0.f,0.f,0.f,0.f,0.f,0.f,0.f,0.f}

// ---------- prep: x [n][c][t] f32 -> xhi/xlo [n][t][256] bf16 ----------
__global__ __launch_bounds__(256) void prep_x(const float* __restrict__ x,
                                              unsigned short* __restrict__ xhi,
                                              unsigned short* __restrict__ xlo)
{
    const int tt = blockIdx.x, cc = blockIdx.y, n = blockIdx.z;
    const int l = threadIdx.x & 63, cw = threadIdx.x >> 6;
    const int t = tt * 64 + l;
    const int c0 = cc * 64 + cw * 16;

    unsigned ph[8], pl[8];
#pragma unroll
    for (int j = 0; j < 8; j++) {
        float f0 = x[((size_t)n * 256 + c0 + 2*j) * S_LEN + t];
        float f1 = x[((size_t)n * 256 + c0 + 2*j + 1) * S_LEN + t];
        unsigned short h0 = f2bf(f0), h1 = f2bf(f1);
        ph[j] = (unsigned)h0 | ((unsigned)h1 << 16);
        pl[j] = (unsigned)f2bf(f0 - bf2f(h0)) | ((unsigned)f2bf(f1 - bf2f(h1)) << 16);
    }
    size_t o = ((size_t)n * S_LEN + t) * 256 + c0;
    *(u32x4*)(xhi + o)     = (u32x4){ph[0], ph[1], ph[2], ph[3]};
    *(u32x4*)(xhi + o + 8) = (u32x4){ph[4], ph[5], ph[6], ph[7]};
    *(u32x4*)(xlo + o)     = (u32x4){pl[0], pl[1], pl[2], pl[3]};
    *(u32x4*)(xlo + o + 8) = (u32x4){pl[4], pl[5], pl[6], pl[7]};
}

// ---------- wprep: Wv->bf16 [d][c]; Wq/Wk -> hi/lo packed B-frag layout ----------
__global__ __launch_bounds__(256) void wprep(const float* __restrict__ Wq,
                                             const float* __restrict__ Wk,
                                             const float* __restrict__ Wv,
                                             unsigned short* __restrict__ wvbf,
                                             unsigned short* __restrict__ wqh,
                                             unsigned short* __restrict__ wql,
                                             unsigned short* __restrict__ wkh,
                                             unsigned short* __restrict__ wkl)
{
    const int b = blockIdx.x;
    if (b < 64) {
        int i = b * 1024 + threadIdx.x * 4;
        f32x4 w = *(const f32x4*)(Wv + i);
        u32x2 pk;
        pk[0] = pk2(w[0], w[1]);
        pk[1] = pk2(w[2], w[3]);
        *(u32x2*)(wvbf + i) = pk;
    } else {
        const float* Wsrc = (b == 64) ? Wq : Wk;
        float scale = (b == 64) ? LOG2E : 1.f;
        unsigned short* oh = (b == 64) ? wqh : wkh;
        unsigned short* ol = (b == 64) ? wql : wkl;
        int t = threadIdx.x;
#pragma unroll
        for (int ii = 0; ii < 4; ii++) {
            int ent = t * 4 + ii;                 // ent = (kc*2+h)*32 + m
            int m = ent & 31, hh = (ent >> 5) & 1, kc = ent >> 6;
#pragma unroll
            for (int e = 0; e < 8; e++) {
                int c = kc * 16 + hh * 8 + e;
                float wv = Wsrc[m * 256 + c] * scale;
                unsigned short wh = f2bf(wv);
                oh[ent * 8 + e] = wh;
                ol[ent * 8 + e] = f2bf(wv - bf2f(wh));
            }
        }
    }
}

// ---------- Q/K projection: split-bf16 MFMA GEMM (fp32-class accuracy) ----------
__global__ __launch_bounds__(256) void qk_gemm(
    const unsigned short* __restrict__ xhi, const unsigned short* __restrict__ xlo,
    const unsigned short* __restrict__ wqh, const unsigned short* __restrict__ wql,
    const unsigned short* __restrict__ wkh, const unsigned short* __restrict__ wkl,
    const float* __restrict__ bq, const float* __restrict__ bk,
    unsigned short* __restrict__ qt_hi, unsigned short* __restrict__ qt_lo,
    unsigned short* __restrict__ kt_hi, unsigned short* __restrict__ kt_lo)
{
    const int wv = threadIdx.x >> 6, l = threadIdx.x & 63;
    const int l31 = l & 31, h = l >> 5;
    const int tile = blockIdx.x * 4 + wv;
    const int n = tile >> 7, t0 = (tile & 127) * 32;

    f32x16 aQ = Z16, aK = Z16;
    const unsigned short* xr  = xhi + ((size_t)n * S_LEN + t0 + l31) * 256 + 8 * h;
    const unsigned short* xr2 = xlo + ((size_t)n * S_LEN + t0 + l31) * 256 + 8 * h;

#pragma unroll
    for (int kc = 0; kc < 16; kc++) {
        short8 ah = *(const short8*)(xr  + kc * 16);
        short8 al = *(const short8*)(xr2 + kc * 16);
        int wb = ((kc * 2 + h) * 32 + l31) * 8;
        short8 bqh = *(const short8*)(wqh + wb);
        short8 bql = *(const short8*)(wql + wb);
        short8 bkh = *(const short8*)(wkh + wb);
        short8 bkl = *(const short8*)(wkl + wb);
        aQ = __builtin_amdgcn_mfma_f32_32x32x16_bf16(ah, bqh, aQ, 0, 0, 0);
        aQ = __builtin_amdgcn_mfma_f32_32x32x16_bf16(al, bqh, aQ, 0, 0, 0);
        aQ = __builtin_amdgcn_mfma_f32_32x32x16_bf16(ah, bql, aQ, 0, 0, 0);
        aK = __builtin_amdgcn_mfma_f32_32x32x16_bf16(ah, bkh, aK, 0, 0, 0);
        aK = __builtin_amdgcn_mfma_f32_32x32x16_bf16(al, bkh, aK, 0, 0, 0);
        aK = __builtin_amdgcn_mfma_f32_32x32x16_bf16(ah, bkl, aK, 0, 0, 0);
    }

    float bqv = bq[l31] * LOG2E, bkv = bk[l31];
    size_t ob = (size_t)n * S_LEN + t0;
#pragma unroll
    for (int r = 0; r < 16; r++) {
        int trow = (r & 3) + 8 * (r >> 2) + 4 * h;
        size_t o = (ob + trow) * 32 + l31;
        float qv = aQ[r] + bqv;
        unsigned short qh16 = f2bf(qv);
        qt_hi[o] = qh16;
        qt_lo[o] = f2bf(qv - bf2f(qh16));
        float kv = aK[r] + bkv;
        unsigned short kh16 = f2bf(kv);
        kt_hi[o] = kh16;
        kt_lo[o] = f2bf(kv - bf2f(kh16));
    }
}

// ---------- V projection: bf16 MFMA GEMM, V[n][d][t] ----------
__global__ __launch_bounds__(256) void v_gemm(
    const unsigned short* __restrict__ xbf, const unsigned short* __restrict__ wvbf,
    const float* __restrict__ bv, unsigned short* __restrict__ V)
{
    const int n = blockIdx.y, t0 = blockIdx.x * 64;
    const int w = threadIdx.x >> 6, l = threadIdx.x & 63;
    const int l16 = l & 15, lq = l >> 4;

    f32x4 acc[16];
#pragma unroll
    for (int i = 0; i < 16; i++) acc[i] = (f32x4){0.f, 0.f, 0.f, 0.f};

    const unsigned short* xrow = xbf + ((size_t)n * S_LEN + t0 + w * 16 + l16) * 256;
#pragma unroll
    for (int kk = 0; kk < 8; kk++) {
        short8 a = *(const short8*)(xrow + kk * 32 + lq * 8);
#pragma unroll
        for (int df = 0; df < 16; df++) {
            short8 b = *(const short8*)(wvbf + (size_t)(df * 16 + l16) * 256 + kk * 32 + lq * 8);
            acc[df] = __builtin_amdgcn_mfma_f32_16x16x32_bf16(a, b, acc[df], 0, 0, 0);
        }
    }
    const int tb = t0 + w * 16 + lq * 4;
#pragma unroll
    for (int df = 0; df < 16; df++) {
        int d = df * 16 + l16;
        float bvv = bv[d];
        u32x2 pk;
        pk[0] = pk2(acc[df][0] + bvv, acc[df][1] + bvv);
        pk[1] = pk2(acc[df][2] + bvv, acc[df][3] + bvv);
        *(u32x2*)(V + ((size_t)n * 256 + d) * S_LEN + tb) = pk;
    }
}

// ---------- flash attention: 8 symmetric waves, in-reg softmax/P, 1 barrier/iter ----------
__global__ __launch_bounds__(512, 2) void attn(
    const unsigned short* __restrict__ qt_hi, const unsigned short* __restrict__ qt_lo,
    const unsigned short* __restrict__ kt_hi, const unsigned short* __restrict__ kt_lo,
    const unsigned short* __restrict__ V, const float* __restrict__ x,
    const float* __restrict__ gamma, float* __restrict__ out)
{
    const int bid = blockIdx.x;
    const int n = bid & 3;                 // n pinned per XCD (bid%8 -> XCD, xcd&3 = n)
    const int S0 = (bid >> 2) * 64;
    const int tid = threadIdx.x;
    const int w = tid >> 6, l = tid & 63;
    const int i = w & 1, q = w >> 1;       // s-chunk, t-quarter
    const int l31 = l & 31, h = l >> 5;

    __shared__ __align__(16) unsigned char vst[4][2][16384];  // 128KB V tiles
    __shared__ float mlds[4][2][2][32];

    // Q B-fragments (hi/lo x 2 k-chunks), s = S0 + i*32 + l31 lane-local
    const int si0 = S0 + i * 32;
    const size_t qb = ((size_t)n * S_LEN + si0 + l31) * 32 + 8 * h;
    const short8 qh0 = *(const short8*)(qt_hi + qb);
    const short8 qh1 = *(const short8*)(qt_hi + qb + 16);
    const short8 ql0 = *(const short8*)(qt_lo + qb);
    const short8 ql1 = *(const short8*)(qt_lo + qb + 16);

    f32x16 acc[8];
#pragma unroll
    for (int dt = 0; dt < 8; dt++) acc[dt] = (f32x16)Z16;
    float m_run = -__builtin_inff(), l_run = 0.f;

    const unsigned char* Vn = (const unsigned char*)(V + (size_t)n * 256 * S_LEN);
    const unsigned short* Kh = kt_hi + (size_t)n * S_LEN * 32;
    const unsigned short* Kl = kt_lo + (size_t)n * S_LEN * 32;

    const int dL = i * 128 + (l >> 2);     // staging d-row base
    const int bL = (l & 3) * 16;           // staging byte-in-row
    unsigned char* myv = &vst[q][0][0];

    // ---- prologue: K(0) regs, V(0) -> LDS ----
    short8 kh0, kh1, kl0, kl1;
    {
        size_t kb = (size_t)(q * 1024 + l31) * 32 + 8 * h;
        kh0 = *(const short8*)(Kh + kb);       kh1 = *(const short8*)(Kh + kb + 16);
        kl0 = *(const short8*)(Kl + kb);       kl1 = *(const short8*)(Kl + kb + 16);
        short8 vr[8];
        size_t tB = (size_t)(q * 1024) * 2;
#pragma unroll
        for (int j = 0; j < 8; j++)
            vr[j] = *(const short8*)(Vn + (size_t)(dL + j * 16) * 8192 + tB + bL);
#pragma unroll
        for (int j = 0; j < 8; j++) {
            int d = dL + j * 16;
            *(short8*)(myv + d * 64 + (bL ^ ((d & 3) << 4))) = vr[j];
        }
    }
    __syncthreads();

    int cur = 0;
    for (int it = 0; it < 32; ++it) {
        const bool more = (it < 31);
        // ---- prefetch next K + V (issue early) ----
        short8 nkh0, nkh1, nkl0, nkl1, vr[8];
        if (more) {
            size_t kb = (size_t)(q * 1024 + (it + 1) * 32 + l31) * 32 + 8 * h;
            nkh0 = *(const short8*)(Kh + kb);   nkh1 = *(const short8*)(Kh + kb + 16);
            nkl0 = *(const short8*)(Kl + kb);   nkl1 = *(const short8*)(Kl + kb + 16);
            size_t tB = (size_t)(q * 1024 + (it + 1) * 32) * 2;
#pragma unroll
            for (int j = 0; j < 8; j++)
                vr[j] = *(const short8*)(Vn + (size_t)(dL + j * 16) * 8192 + tB + bL);
        }

        // ---- swapped QK^T: D[t][s], s = l31 lane-local ----
        f32x16 sD = Z16;
        sD = __builtin_amdgcn_mfma_f32_32x32x16_bf16(kh0, qh0, sD, 0, 0, 0);
        sD = __builtin_amdgcn_mfma_f32_32x32x16_bf16(kh0, ql0, sD, 0, 0, 0);
        sD = __builtin_amdgcn_mfma_f32_32x32x16_bf16(kl0, qh0, sD, 0, 0, 0);
        sD = __builtin_amdgcn_mfma_f32_32x32x16_bf16(kh1, qh1, sD, 0, 0, 0);
        sD = __builtin_amdgcn_mfma_f32_32x32x16_bf16(kh1, ql1, sD, 0, 0, 0);
        sD = __builtin_amdgcn_mfma_f32_32x32x16_bf16(kl1, qh1, sD, 0, 0, 0);

        // ---- online softmax (log2 domain), defer-max ----
        float a0 = fmaxf(sD[0], sD[1]),  a1 = fmaxf(sD[2], sD[3]);
        float a2 = fmaxf(sD[4], sD[5]),  a3 = fmaxf(sD[6], sD[7]);
        float a4 = fmaxf(sD[8], sD[9]),  a5 = fmaxf(sD[10], sD[11]);
        float a6 = fmaxf(sD[12], sD[13]), a7 = fmaxf(sD[14], sD[15]);
        float tmax = fmaxf(fmaxf(fmaxf(a0, a1), fmaxf(a2, a3)),
                           fmaxf(fmaxf(a4, a5), fmaxf(a6, a7)));
        tmax = fmaxf(tmax, __shfl_xor(tmax, 32));
        if (!__all(tmax <= m_run + 11.0f)) {
            float mn = fmaxf(m_run, tmax);
            float al = exp2f(m_run - mn);
#pragma unroll
            for (int dt = 0; dt < 8; dt++) acc[dt] *= al;
            l_run *= al;
            m_run = mn;
        }
        float pe[16];
#pragma unroll
        for (int r = 0; r < 16; r++) pe[r] = exp2f(sD[r] - m_run);
        float ls = ((pe[0] + pe[1]) + (pe[2] + pe[3])) + ((pe[4] + pe[5]) + (pe[6] + pe[7]))
                 + ((pe[8] + pe[9]) + (pe[10] + pe[11])) + ((pe[12] + pe[13]) + (pe[14] + pe[15]));
        ls += __shfl_xor(ls, 32);
        l_run += ls;

        // ---- P -> bf16 A/B fragments, in-register (pk pairs + xor-32 exchange) ----
        unsigned pb[8];
#pragma unroll
        for (int i2 = 0; i2 < 8; i2++) pb[i2] = pk2(pe[2 * i2], pe[2 * i2 + 1]);
        short8 pa[2];
#pragma unroll
        for (int c = 0; c < 2; c++) {
            unsigned s0 = h ? pb[4 * c + 0] : pb[4 * c + 2];
            unsigned s1 = h ? pb[4 * c + 1] : pb[4 * c + 3];
            unsigned r0 = __shfl_xor(s0, 32);
            unsigned r1 = __shfl_xor(s1, 32);
            S8U cv;
            cv.u[0] = h ? r0 : pb[4 * c + 0];
            cv.u[1] = h ? r1 : pb[4 * c + 1];
            cv.u[2] = h ? pb[4 * c + 2] : r0;
            cv.u[3] = h ? pb[4 * c + 3] : r1;
            pa[c] = cv.s;
        }

        // ---- PV: O^T[d][s] += V'[d][t] * P'[t][s] ----
        const unsigned char* vb = &vst[q][cur][0];
#pragma unroll
        for (int c = 0; c < 2; c++) {
#pragma unroll
            for (int dt = 0; dt < 8; dt++) {
                int d = dt * 32 + l31;
                short8 vf = *(const short8*)(vb + d * 64 + ((c * 32 + 16 * h) ^ ((d & 3) << 4)));
                acc[dt] = __builtin_amdgcn_mfma_f32_32x32x16_bf16(vf, pa[c], acc[dt], 0, 0, 0);
            }
        }

        // ---- write prefetched V tile (write-late), single barrier ----
        if (more) {
            unsigned char* db = &vst[q][cur ^ 1][0];
#pragma unroll
            for (int j = 0; j < 8; j++) {
                int d = dL + j * 16;
                *(short8*)(db + d * 64 + (bL ^ ((d & 3) << 4))) = vr[j];
            }
            kh0 = nkh0; kh1 = nkh1; kl0 = nkl0; kl1 = nkl1;
        }
        __syncthreads();
        cur ^= 1;
    }

    // ---- merge quarters ----
    if (h == 0) { mlds[q][i][0][l31] = m_run; mlds[q][i][1][l31] = l_run; }
    __syncthreads();

    float* mrg = (float*)&vst[0][0][0];
    float M = 0.f, rden = 0.f;
    if (q == 0) {
        float m0 = mlds[0][i][0][l31], m1 = mlds[1][i][0][l31];
        float m2 = mlds[2][i][0][l31], m3 = mlds[3][i][0][l31];
        M = fmaxf(fmaxf(m0, m1), fmaxf(m2, m3));
        rden = mlds[0][i][1][l31] * exp2f(m0 - M) + mlds[1][i][1][l31] * exp2f(m1 - M)
             + mlds[2][i][1][l31] * exp2f(m2 - M) + mlds[3][i][1][l31] * exp2f(m3 - M);
        rden = 1.f / rden;
        float sc = exp2f(m_run - M);
#pragma unroll
        for (int dt = 0; dt < 8; dt++) acc[dt] *= sc;
    }
#pragma unroll
    for (int r = 1; r < 4; r++) {
        if (q == r) {
            float* mb = mrg + i * 8192;
#pragma unroll
            for (int dt = 0; dt < 8; dt++)
#pragma unroll
                for (int qd = 0; qd < 4; qd++) {
                    f32x4 v = { acc[dt][4*qd], acc[dt][4*qd+1], acc[dt][4*qd+2], acc[dt][4*qd+3] };
                    *(f32x4*)(mb + (dt * 4 + qd) * 256 + l * 4) = v;
                }
        }
        __syncthreads();
        if (q == 0) {
            float sc = exp2f(mlds[r][i][0][l31] - M);
            const float* mb = mrg + i * 8192;
#pragma unroll
            for (int dt = 0; dt < 8; dt++)
#pragma unroll
                for (int qd = 0; qd < 4; qd++) {
                    f32x4 v = *(const f32x4*)(mb + (dt * 4 + qd) * 256 + l * 4);
                    acc[dt][4*qd]   += v[0] * sc;
                    acc[dt][4*qd+1] += v[1] * sc;
                    acc[dt][4*qd+2] += v[2] * sc;
                    acc[dt][4*qd+3] += v[3] * sc;
                }
        }
        __syncthreads();
    }

    if (q == 0) {
        const float g = gamma[0];
        const int s = si0 + l31;
#pragma unroll
        for (int dt = 0; dt < 8; dt++)
#pragma unroll
            for (int r2 = 0; r2 < 16; r2++) {
                int d = dt * 32 + (r2 & 3) + 8 * (r2 >> 2) + 4 * h;
                size_t idx = ((size_t)n * 256 + d) * S_LEN + s;
                out[idx] = x[idx] + g * acc[dt][r2] * rden;
            }
    }
}

extern "C" void kernel_launch(void* const* d_in, const int* in_sizes, int n_in,
                              void* d_out, int out_size, void* d_ws, size_t ws_size,
                              hipStream_t stream) {
    const float* x     = (const float*)d_in[0];
    const float* Wq    = (const float*)d_in[1];
    const float* bq    = (const float*)d_in[2];
    const float* Wk    = (const float*)d_in[3];
    const float* bk    = (const float*)d_in[4];
    const float* Wv    = (const float*)d_in[5];
    const float* bv    = (const float*)d_in[6];
    const float* gamma = (const float*)d_in[7];
    float* out = (float*)d_out;

    unsigned char* ws = (unsigned char*)d_ws;
    unsigned short* xhi   = (unsigned short*)(ws + OFF_XHI);
    unsigned short* xlo   = (unsigned short*)(ws + OFF_XLO_V);  // aliased with V
    unsigned short* V     = (unsigned short*)(ws + OFF_XLO_V);
    unsigned short* qt_hi = (unsigned short*)(ws + OFF_QT_HI);
    unsigned short* qt_lo = (unsigned short*)(ws + OFF_QT_LO);
    unsigned short* kt_hi = (unsigned short*)(ws + OFF_KT_HI);
    unsigned short* kt_lo = (unsigned short*)(ws + OFF_KT_LO);
    unsigned short* wvbf  = (unsigned short*)(ws + OFF_WVBF);
    unsigned short* wqh   = (unsigned short*)(ws + OFF_WQH);
    unsigned short* wql   = (unsigned short*)(ws + OFF_WQL);
    unsigned short* wkh   = (unsigned short*)(ws + OFF_WKH);
    unsigned short* wkl   = (unsigned short*)(ws + OFF_WKL);

    prep_x<<<dim3(64, 4, 4), dim3(256), 0, stream>>>(x, xhi, xlo);
    wprep<<<dim3(66), dim3(256), 0, stream>>>(Wq, Wk, Wv, wvbf, wqh, wql, wkh, wkl);
    qk_gemm<<<dim3(128), dim3(256), 0, stream>>>(xhi, xlo, wqh, wql, wkh, wkl, bq, bk,
                                                 qt_hi, qt_lo, kt_hi, kt_lo);
    v_gemm<<<dim3(64, 4), dim3(256), 0, stream>>>(xhi, wvbf, bv, V);   // overwrites xlo
    attn<<<dim3(256), dim3(512), 0, stream>>>(qt_hi, qt_lo, kt_hi, kt_lo, V,
                                              x, gamma, out);
}